// Round 5
// baseline (757.423 us; speedup 1.0000x reference)
//
#include <hip/hip_runtime.h>
#include <stdint.h>

// JointSlotFusion on MI355X (gfx950).
// ws layout (bytes):
//   kbuf  bf16[128][2048][64] @ 0           (33,554,432)  token-major
//   vT    bf16[128][64][2048] @ 33,554,432  (33,554,432)  d-major
//   wconv bf16[2][64][256]    @ 67,108,864  (65,536)
//   wkv   bf16[2][64][64]     @ 67,174,400  (16,384)
//   sb0   f32[128][8][64]     @ 67,190,784  (262,144)
//   sb1   f32[128][8][64]     @ 67,452,928  (262,144)
//   updA  bf16[128][16][512]  @ 67,715,072  (2,097,152)
//   updB  bf16[128][16][512]  @ 69,812,224  (2,097,152)
//   colA  f32[128][16][8]     @ 71,909,376  (65,536)
//   colB  f32[128][16][8]     @ 71,974,912  (65,536)
// total 72,040,448

typedef __bf16 bf16;
typedef __bf16 bf16x8 __attribute__((ext_vector_type(8)));
typedef float  f32x4  __attribute__((ext_vector_type(4)));

#define MFMA16(a, b, c) __builtin_amdgcn_mfma_f32_16x16x32_bf16((a), (b), (c), 0, 0, 0)

#define ASYNC_LDS16(g, l) \
  __builtin_amdgcn_global_load_lds((const __attribute__((address_space(1))) void*)(g), \
                                   (__attribute__((address_space(3))) void*)(l), 16, 0, 0)

union Scr {   // 8,192 B scratch, phases strictly sequential
  struct { float sr[8][64], sz[8][64], inn[8][64], hn[8][64]; } g;
  float h1[8][132];
  float updp[4][8][64];
};

// ---------------- K0: weight fp32 -> bf16 ----------------
__global__ __launch_bounds__(256) void k0_convert(
    const float* __restrict__ c1w, const float* __restrict__ c2w,
    const float* __restrict__ wk,  const float* __restrict__ wvv,
    bf16* __restrict__ wconv, bf16* __restrict__ wkv)
{
  const int i = blockIdx.x * 256 + threadIdx.x;
  if (i < 16384) {
    wconv[i]         = (bf16)c1w[i];
    wconv[16384 + i] = (bf16)c2w[i];
  }
  if (i < 4096) {
    wkv[i]        = (bf16)wk[i];
    wkv[4096 + i] = (bf16)wvv[i];
  }
}

// ---------------- K1: conv1x1 + LN + LN + k/v GEMM ----------------
// grid 4096 = 128 b * 2 img * 16 pixel-tiles of 64; block 256 (4 waves).
// K staged in 8 steps of 32 channels in one 8.4 KB buffer; epilogue reuses a
// single 16.6 KB union -> 8 blocks/CU (wave cap).
__global__ __launch_bounds__(256) void k1_conv_kv(
    const float* __restrict__ x1, const float* __restrict__ x2,
    const float* __restrict__ c1b, const float* __restrict__ c2b,
    const float* __restrict__ nw,  const float* __restrict__ nb,
    const float* __restrict__ niw, const float* __restrict__ nib,
    const bf16* __restrict__ wconv, const bf16* __restrict__ wkv,
    bf16* __restrict__ kbuf, bf16* __restrict__ vT)
{
  __shared__ union {
    float xs[8 * 264];    // 8,448 B: one 32-channel staging step
    float T[64][65];      // 16,640 B fp32 tile
    bf16  tok[64][72];    // 9,216 B LN'd tokens
  } U;

  const int bx   = blockIdx.x;
  const int tile = bx & 15;
  const int img  = (bx >> 4) & 1;
  const int b    = bx >> 5;
  const int tid  = threadIdx.x;
  const int lane = tid & 63;
  const int wvid = tid >> 6;
  const int l15  = lane & 15;
  const int quad = lane >> 4;

  const float* xp   = (img ? x2 : x1) + (size_t)b * (256 * 1024) + tile * 64;
  const int   rowin = lane >> 4;
  const int   pq    = (lane & 15) * 4;
  const float* ga0  = xp + (size_t)rowin * 1024 + pq;
  const bf16* wc    = wconv + img * (64 * 256);
  const int p = wvid * 16 + l15;

  f32x4 acc[4] = {{0.f,0.f,0.f,0.f},{0.f,0.f,0.f,0.f},{0.f,0.f,0.f,0.f},{0.f,0.f,0.f,0.f}};

  for (int step = 0; step < 8; ++step) {
    #pragma unroll
    for (int gi = 0; gi < 2; ++gi) {
      const int g = wvid * 2 + gi;
      ASYNC_LDS16(ga0 + (size_t)(step * 32 + g * 4) * 1024, &U.xs[g * 264]);
    }
    __syncthreads();
    bf16x8 af;
    #pragma unroll
    for (int j = 0; j < 8; ++j) {
      const int cl = quad * 8 + j;
      af[j] = (bf16)U.xs[(cl >> 2) * 264 + (cl & 3) * 64 + p];
    }
    #pragma unroll
    for (int nt = 0; nt < 4; ++nt) {
      const bf16x8 bw = *(const bf16x8*)&wc[(nt * 16 + l15) * 256 + step * 32 + quad * 8];
      acc[nt] = MFMA16(af, bw, acc[nt]);
    }
    __syncthreads();   // xs consumed before next stage / reuse
  }

  // bias + park in fp32 tile
  {
    const float* cb = img ? c2b : c1b;
    #pragma unroll
    for (int nt = 0; nt < 4; ++nt) {
      const int d = nt * 16 + l15;
      const float bias = cb[d];
      #pragma unroll
      for (int r = 0; r < 4; ++r)
        U.T[wvid * 16 + quad * 4 + r][d] = acc[nt][r] + bias;
    }
  }
  __syncthreads();

  // Double LayerNorm: read T -> regs
  float yv[16];
  {
    const int pix = tid >> 2, part = tid & 3;
    float xv[16];
    float s = 0.f, s2 = 0.f;
    #pragma unroll
    for (int i = 0; i < 16; ++i) {
      xv[i] = U.T[pix][part * 16 + i];
      s += xv[i]; s2 += xv[i] * xv[i];
    }
    s  += __shfl_xor(s, 1);  s  += __shfl_xor(s, 2);
    s2 += __shfl_xor(s2, 1); s2 += __shfl_xor(s2, 2);
    float mu   = s * 0.015625f;
    float rstd = rsqrtf(s2 * 0.015625f - mu * mu + 1e-5f);
    s = 0.f; s2 = 0.f;
    #pragma unroll
    for (int i = 0; i < 16; ++i) {
      const int d = part * 16 + i;
      const float y = (xv[i] - mu) * rstd * nw[d] + nb[d];
      yv[i] = y; s += y; s2 += y * y;
    }
    s  += __shfl_xor(s, 1);  s  += __shfl_xor(s, 2);
    s2 += __shfl_xor(s2, 1); s2 += __shfl_xor(s2, 2);
    mu   = s * 0.015625f;
    rstd = rsqrtf(s2 * 0.015625f - mu * mu + 1e-5f);
    #pragma unroll
    for (int i = 0; i < 16; ++i) {
      const int d = part * 16 + i;
      yv[i] = (yv[i] - mu) * rstd * niw[d] + nib[d];
    }
  }
  __syncthreads();   // T dead
  {
    const int pix = tid >> 2, part = tid & 3;
    #pragma unroll
    for (int i = 0; i < 16; ++i) U.tok[pix][part * 16 + i] = (bf16)yv[i];
  }
  __syncthreads();

  // k/v GEMMs: K=64
  f32x4 ak[4] = {{0.f,0.f,0.f,0.f},{0.f,0.f,0.f,0.f},{0.f,0.f,0.f,0.f},{0.f,0.f,0.f,0.f}};
  f32x4 av[4] = {{0.f,0.f,0.f,0.f},{0.f,0.f,0.f,0.f},{0.f,0.f,0.f,0.f},{0.f,0.f,0.f,0.f}};
  #pragma unroll
  for (int k0 = 0; k0 < 64; k0 += 32) {
    const bf16x8 af = *(const bf16x8*)&U.tok[wvid * 16 + l15][k0 + quad * 8];
    #pragma unroll
    for (int nt = 0; nt < 4; ++nt) {
      const bf16x8 bk = *(const bf16x8*)&wkv[(nt * 16 + l15) * 64 + k0 + quad * 8];
      const bf16x8 bv = *(const bf16x8*)&wkv[4096 + (nt * 16 + l15) * 64 + k0 + quad * 8];
      ak[nt] = MFMA16(af, bk, ak[nt]);
      av[nt] = MFMA16(af, bv, av[nt]);
    }
  }
  __syncthreads();   // tok dead

  // k repack (pixel-major) through T, store
  #pragma unroll
  for (int nt = 0; nt < 4; ++nt)
    #pragma unroll
    for (int r = 0; r < 4; ++r)
      U.T[wvid * 16 + quad * 4 + r][nt * 16 + l15] = ak[nt][r];
  __syncthreads();
  {
    const int row = tid >> 2, dd = (tid & 3) * 16;
    const size_t kb = ((size_t)b * 2048 + img * 1024 + tile * 64) * 64;
    bf16 tb[16];
    #pragma unroll
    for (int i = 0; i < 16; ++i) tb[i] = (bf16)U.T[row][dd + i];
    *(bf16x8*)&kbuf[kb + (size_t)row * 64 + dd]     = *(bf16x8*)&tb[0];
    *(bf16x8*)&kbuf[kb + (size_t)row * 64 + dd + 8] = *(bf16x8*)&tb[8];
  }
  __syncthreads();
  // v repack (d-major) through T, store
  #pragma unroll
  for (int nt = 0; nt < 4; ++nt)
    #pragma unroll
    for (int r = 0; r < 4; ++r)
      U.T[nt * 16 + l15][wvid * 16 + quad * 4 + r] = av[nt][r];
  __syncthreads();
  {
    const int row = tid >> 2, dd = (tid & 3) * 16;
    bf16 tb[16];
    #pragma unroll
    for (int i = 0; i < 16; ++i) tb[i] = (bf16)U.T[row][dd + i];
    const size_t vb = ((size_t)b * 64 + row) * 2048 + img * 1024 + tile * 64 + dd;
    *(bf16x8*)&vT[vb]     = *(bf16x8*)&tb[0];
    *(bf16x8*)&vT[vb + 8] = *(bf16x8*)&tb[8];
  }
}

// ---------------- shared slot math (256-thread blocks) ----------------

// GRU + residual MLP: tmp = updates, slots = slots_prev on entry;
// slots = new slots on exit. Uses scr (g then h1). ~5 barriers.
__device__ __forceinline__ void gru_mlp_update(
    int tid, float (*slots)[66], float (*tmp)[66], Scr* scr,
    const float* __restrict__ wih, const float* __restrict__ whh,
    const float* __restrict__ bih, const float* __restrict__ bhh,
    const float* __restrict__ w1,  const float* __restrict__ b1,
    const float* __restrict__ w2,  const float* __restrict__ b2,
    const float* __restrict__ nmw, const float* __restrict__ nmb)
{
  const int lane = tid & 63, wv = tid >> 6;
  const int part = lane & 7, sl = lane >> 3;

  // gates: wave wv handles j = jr*4+wv for all 8 slots (broadcast weight rows)
  {
    float tv[8], sv[8];
    #pragma unroll
    for (int i = 0; i < 8; ++i) { tv[i] = tmp[sl][part * 8 + i]; sv[i] = slots[sl][part * 8 + i]; }
    for (int jr = 0; jr < 48; ++jr) {
      const int j = jr * 4 + wv;
      const f32x4 wa0 = *(const f32x4*)&wih[j * 64 + part * 8];
      const f32x4 wa1 = *(const f32x4*)&wih[j * 64 + part * 8 + 4];
      const f32x4 wb0 = *(const f32x4*)&whh[j * 64 + part * 8];
      const f32x4 wb1 = *(const f32x4*)&whh[j * 64 + part * 8 + 4];
      float a = tv[0]*wa0[0] + tv[1]*wa0[1] + tv[2]*wa0[2] + tv[3]*wa0[3]
              + tv[4]*wa1[0] + tv[5]*wa1[1] + tv[6]*wa1[2] + tv[7]*wa1[3];
      float h = sv[0]*wb0[0] + sv[1]*wb0[1] + sv[2]*wb0[2] + sv[3]*wb0[3]
              + sv[4]*wb1[0] + sv[5]*wb1[1] + sv[6]*wb1[2] + sv[7]*wb1[3];
      a += __shfl_xor(a, 1); a += __shfl_xor(a, 2); a += __shfl_xor(a, 4);
      h += __shfl_xor(h, 1); h += __shfl_xor(h, 2); h += __shfl_xor(h, 4);
      if (part == 0) {
        const float gi_ = a + bih[j], gh_ = h + bhh[j];
        if (j < 64)       scr->g.sr[sl][j] = gi_ + gh_;
        else if (j < 128) scr->g.sz[sl][j - 64] = gi_ + gh_;
        else { scr->g.inn[sl][j - 128] = gi_; scr->g.hn[sl][j - 128] = gh_; }
      }
    }
  }
  __syncthreads();
  // combine
  for (int i = tid; i < 512; i += 256) {
    const int s = i >> 6, d = i & 63;
    const float r  = 1.f / (1.f + expf(-scr->g.sr[s][d]));
    const float z  = 1.f / (1.f + expf(-scr->g.sz[s][d]));
    const float nn = tanhf(scr->g.inn[s][d] + r * scr->g.hn[s][d]);
    slots[s][d] = (1.f - z) * nn + z * slots[s][d];
  }
  __syncthreads();
  // LN(nm) -> tmp
  for (int rr = wv; rr < 8; rr += 4) {
    const float v = slots[rr][lane];
    float s = v, s2 = v * v;
    #pragma unroll
    for (int m = 1; m < 64; m <<= 1) { s += __shfl_xor(s, m); s2 += __shfl_xor(s2, m); }
    const float mu = s * 0.015625f;
    const float rstd = rsqrtf(s2 * 0.015625f - mu * mu + 1e-5f);
    tmp[rr][lane] = (v - mu) * rstd * nmw[lane] + nmb[lane];
  }
  __syncthreads();
  // MLP hidden -> scr->h1 (g dead)
  {
    float tm[8];
    #pragma unroll
    for (int i = 0; i < 8; ++i) tm[i] = tmp[sl][part * 8 + i];
    for (int jr = 0; jr < 32; ++jr) {
      const int j = jr * 4 + wv;
      const f32x4 w0 = *(const f32x4*)&w1[j * 64 + part * 8];
      const f32x4 w1v = *(const f32x4*)&w1[j * 64 + part * 8 + 4];
      float a = tm[0]*w0[0] + tm[1]*w0[1] + tm[2]*w0[2] + tm[3]*w0[3]
              + tm[4]*w1v[0] + tm[5]*w1v[1] + tm[6]*w1v[2] + tm[7]*w1v[3];
      a += __shfl_xor(a, 1); a += __shfl_xor(a, 2); a += __shfl_xor(a, 4);
      if (part == 0) scr->h1[sl][j] = fmaxf(a + b1[j], 0.f);
    }
  }
  __syncthreads();
  // MLP out + residual
  for (int orr = 0; orr < 16; ++orr) {
    const int d = orr * 4 + wv;
    float a = 0.f;
    #pragma unroll
    for (int i = 0; i < 4; ++i) {
      const f32x4 wv4 = *(const f32x4*)&w2[d * 128 + part * 16 + i * 4];
      a += scr->h1[sl][part * 16 + i * 4 + 0] * wv4[0] + scr->h1[sl][part * 16 + i * 4 + 1] * wv4[1]
         + scr->h1[sl][part * 16 + i * 4 + 2] * wv4[2] + scr->h1[sl][part * 16 + i * 4 + 3] * wv4[3];
    }
    a += __shfl_xor(a, 1); a += __shfl_xor(a, 2); a += __shfl_xor(a, 4);
    if (part == 0) slots[sl][d] += a + b2[d];
  }
  __syncthreads();
}

// LN(ns) + q -> qs (bf16, *scale)
__device__ __forceinline__ void ln_q(
    int tid, float (*slots)[66], float (*tmp)[66],
    const float* __restrict__ nsw, const float* __restrict__ nsb,
    const float* __restrict__ Wq, bf16 (*qs)[72])
{
  const int lane = tid & 63, wv = tid >> 6;
  const int part = lane & 7, sl = lane >> 3;
  for (int rr = wv; rr < 8; rr += 4) {
    const float v = slots[rr][lane];
    float s = v, s2 = v * v;
    #pragma unroll
    for (int m = 1; m < 64; m <<= 1) { s += __shfl_xor(s, m); s2 += __shfl_xor(s2, m); }
    const float mu = s * 0.015625f;
    const float rstd = rsqrtf(s2 * 0.015625f - mu * mu + 1e-5f);
    tmp[rr][lane] = (v - mu) * rstd * nsw[lane] + nsb[lane];
  }
  __syncthreads();
  float tm[8];
  #pragma unroll
  for (int i = 0; i < 8; ++i) tm[i] = tmp[sl][part * 8 + i];
  for (int orr = 0; orr < 16; ++orr) {
    const int d = orr * 4 + wv;
    const f32x4 w0 = *(const f32x4*)&Wq[d * 64 + part * 8];
    const f32x4 w1v = *(const f32x4*)&Wq[d * 64 + part * 8 + 4];
    float a = tm[0]*w0[0] + tm[1]*w0[1] + tm[2]*w0[2] + tm[3]*w0[3]
            + tm[4]*w1v[0] + tm[5]*w1v[1] + tm[6]*w1v[2] + tm[7]*w1v[3];
    a += __shfl_xor(a, 1); a += __shfl_xor(a, 2); a += __shfl_xor(a, 4);
    if (part == 0) qs[sl][d] = (bf16)(a * 0.125f);
  }
  __syncthreads();
}

// ---------------- kA: fused slot-update prologue + logits/softmax/PV ----------------
// grid 2048 = 128 b * 16 chunks of 128 tokens; block 256.
// mode 0: init slots from noise; mode 1: GRU/MLP update from updIn/colIn/sbIn.
// chunk-0 block writes sbOut. All blocks write updOut/colOut for their chunk.
__global__ __launch_bounds__(256) void kA(
    const int mode,
    const bf16* __restrict__ kbuf, const bf16* __restrict__ vT,
    const float* __restrict__ smu, const float* __restrict__ slog,
    const float* __restrict__ noise,
    const float* __restrict__ nsw, const float* __restrict__ nsb,
    const float* __restrict__ nmw, const float* __restrict__ nmb,
    const float* __restrict__ Wq,
    const float* __restrict__ wih, const float* __restrict__ whh,
    const float* __restrict__ bih, const float* __restrict__ bhh,
    const float* __restrict__ w1,  const float* __restrict__ b1,
    const float* __restrict__ w2,  const float* __restrict__ b2,
    const float* __restrict__ sbIn, float* __restrict__ sbOut,
    const bf16* __restrict__ updIn, bf16* __restrict__ updOut,
    const float* __restrict__ colIn, float* __restrict__ colOut)
{
  __shared__ float sl_slots[8][66];
  __shared__ float sl_tmp[8][66];
  __shared__ float sl_colsum[8];
  __shared__ Scr   scr;
  __shared__ bf16  qs[16][72];
  __shared__ bf16  attn_b[16][136];
  __shared__ float cspart[4][8];

  const int bx  = blockIdx.x;
  const int b   = bx >> 4, ch = bx & 15;
  const int tid = threadIdx.x;
  const int lane = tid & 63, wvid = tid >> 6;
  const int l15 = lane & 15, quad = lane >> 4;
  const size_t tokbase = (size_t)b * 2048 + ch * 128;

  // zero pad rows of attn (rows 8..15) and qs (rows 8..15, cols 0..63)
  for (int i = tid; i < 544; i += 256) ((uint32_t*)&attn_b[8][0])[i] = 0u;
  { const int r8 = 8 + (tid >> 5), c2 = tid & 31; *(uint32_t*)&qs[r8][c2 * 2] = 0u; }

  // ---- prologue: materialize slots + q in LDS ----
  if (mode == 0) {
    for (int i = tid; i < 512; i += 256) {
      const int s = i >> 6, d = i & 63;
      const float sv = smu[d] + expf(slog[d]) * noise[(size_t)b * 512 + i];
      sl_slots[s][d] = sv;
      if (ch == 0) sbOut[(size_t)b * 512 + i] = sv;
    }
    __syncthreads();
  } else {
    if (tid < 8) {
      float cs = 0.f;
      #pragma unroll
      for (int c = 0; c < 16; ++c) cs += colIn[(size_t)b * 128 + c * 8 + tid];
      sl_colsum[tid] = cs;
    }
    float u[2];
    #pragma unroll
    for (int t = 0; t < 2; ++t) {
      const int i = tid + t * 256;
      float uu = 0.f;
      #pragma unroll
      for (int c = 0; c < 16; ++c) uu += (float)updIn[(size_t)b * 8192 + c * 512 + i];
      u[t] = uu;
      sl_slots[i >> 6][i & 63] = sbIn[(size_t)b * 512 + i];
    }
    __syncthreads();
    #pragma unroll
    for (int t = 0; t < 2; ++t) {
      const int i = tid + t * 256;
      sl_tmp[i >> 6][i & 63] = u[t] / sl_colsum[i >> 6];
    }
    __syncthreads();
    gru_mlp_update(tid, sl_slots, sl_tmp, &scr, wih, whh, bih, bhh,
                   w1, b1, w2, b2, nmw, nmb);
    if (ch == 0)
      for (int i = tid; i < 512; i += 256)
        sbOut[(size_t)b * 512 + i] = sl_slots[i >> 6][i & 63];
  }
  ln_q(tid, sl_slots, sl_tmp, nsw, nsb, Wq, qs);

  // ---- logits (MFMA k @ q^T) + per-token softmax over s ----
  {
    float cs = 0.f;
    #pragma unroll
    for (int mt = 0; mt < 2; ++mt) {
      const int t0 = wvid * 32 + mt * 16;
      const bf16* kr = kbuf + (tokbase + t0 + l15) * 64 + quad * 8;
      f32x4 lg = {0.f, 0.f, 0.f, 0.f};
      lg = MFMA16(*(const bf16x8*)&kr[0],  *(const bf16x8*)&qs[l15][quad * 8],      lg);
      lg = MFMA16(*(const bf16x8*)&kr[32], *(const bf16x8*)&qs[l15][32 + quad * 8], lg);
      #pragma unroll
      for (int r = 0; r < 4; ++r) {
        const float l = lg[r];
        float m = l;
        m = fmaxf(m, __shfl_xor(m, 1));
        m = fmaxf(m, __shfl_xor(m, 2));
        m = fmaxf(m, __shfl_xor(m, 4));
        const float e = expf(l - m);
        float ss = e;
        ss += __shfl_xor(ss, 1);
        ss += __shfl_xor(ss, 2);
        ss += __shfl_xor(ss, 4);
        const float at = e / ss + 1e-8f;
        if (l15 < 8) {
          const bf16 ab = (bf16)at;
          attn_b[l15][t0 + quad * 4 + r] = ab;
          cs += (float)ab;
        }
      }
    }
    cs += __shfl_xor(cs, 16);
    cs += __shfl_xor(cs, 32);
    if (lane < 8) cspart[wvid][lane] = cs;
  }
  __syncthreads();

  // ---- PV via MFMA: A = attn (A-frag-ready), B = vT rows ----
  {
    const bf16x8 afr = *(const bf16x8*)&attn_b[l15][wvid * 32 + quad * 8];
    const bf16* vrow = vT + (size_t)b * 131072 + (size_t)ch * 128 + wvid * 32 + quad * 8;
    const f32x4 zero4 = {0.f, 0.f, 0.f, 0.f};
    #pragma unroll
    for (int nt = 0; nt < 4; ++nt) {
      const bf16x8 bv = *(const bf16x8*)&vrow[(size_t)(nt * 16 + l15) * 2048];
      f32x4 dd = MFMA16(afr, bv, zero4);
      if (quad < 2) {
        #pragma unroll
        for (int r = 0; r < 4; ++r)
          scr.updp[wvid][quad * 4 + r][nt * 16 + l15] = dd[r];
      }
    }
  }
  __syncthreads();
  {
    const float* up = &scr.updp[0][0][0];
    bf16* og = updOut + ((size_t)b * 16 + ch) * 512;
    for (int o = tid; o < 512; o += 256)
      og[o] = (bf16)(up[o] + up[o + 512] + up[o + 1024] + up[o + 1536]);
    if (tid < 8)
      colOut[((size_t)b * 16 + ch) * 8 + tid] =
        cspart[0][tid] + cspart[1][tid] + cspart[2][tid] + cspart[3][tid];
  }
}

// ---------------- kBfin: final slot update + head ----------------
// grid 128, block 256.
__global__ __launch_bounds__(256) void kBfin(
    const float* __restrict__ sbIn,
    const bf16* __restrict__ updIn, const float* __restrict__ colIn,
    const float* __restrict__ wih, const float* __restrict__ whh,
    const float* __restrict__ bih, const float* __restrict__ bhh,
    const float* __restrict__ w1,  const float* __restrict__ b1,
    const float* __restrict__ w2,  const float* __restrict__ b2,
    const float* __restrict__ nmw, const float* __restrict__ nmb,
    const float* __restrict__ hwt, const float* __restrict__ hb,
    float* __restrict__ out)
{
  __shared__ float sl_slots[8][66];
  __shared__ float sl_tmp[8][66];
  __shared__ float sl_colsum[8];
  __shared__ Scr   scr;

  const int b = blockIdx.x, tid = threadIdx.x;

  if (tid < 8) {
    float cs = 0.f;
    #pragma unroll
    for (int c = 0; c < 16; ++c) cs += colIn[(size_t)b * 128 + c * 8 + tid];
    sl_colsum[tid] = cs;
  }
  float u[2];
  #pragma unroll
  for (int t = 0; t < 2; ++t) {
    const int i = tid + t * 256;
    float uu = 0.f;
    #pragma unroll
    for (int c = 0; c < 16; ++c) uu += (float)updIn[(size_t)b * 8192 + c * 512 + i];
    u[t] = uu;
    sl_slots[i >> 6][i & 63] = sbIn[(size_t)b * 512 + i];
  }
  __syncthreads();
  #pragma unroll
  for (int t = 0; t < 2; ++t) {
    const int i = tid + t * 256;
    sl_tmp[i >> 6][i & 63] = u[t] / sl_colsum[i >> 6];
  }
  __syncthreads();
  gru_mlp_update(tid, sl_slots, sl_tmp, &scr, wih, whh, bih, bhh,
                 w1, b1, w2, b2, nmw, nmb);

  if (tid < 64) {
    float f = 0.f;
    #pragma unroll
    for (int s = 0; s < 8; ++s) f += sl_slots[s][tid];
    sl_tmp[0][tid] = f * 0.125f;
  }
  __syncthreads();
  if (tid < 15) {
    float a = hb[tid];
    for (int d = 0; d < 64; ++d) a += sl_tmp[0][d] * hwt[tid * 64 + d];
    out[b * 15 + tid] = a;
  }
}

extern "C" void kernel_launch(void* const* d_in, const int* in_sizes, int n_in,
                              void* d_out, int out_size, void* d_ws, size_t ws_size,
                              hipStream_t stream) {
  const float* x1   = (const float*)d_in[0];
  const float* x2   = (const float*)d_in[1];
  const float* c1w  = (const float*)d_in[2];
  const float* c1b  = (const float*)d_in[3];
  const float* c2w  = (const float*)d_in[4];
  const float* c2b  = (const float*)d_in[5];
  const float* nw   = (const float*)d_in[6];
  const float* nb   = (const float*)d_in[7];
  const float* niw  = (const float*)d_in[8];
  const float* nib  = (const float*)d_in[9];
  const float* nsw  = (const float*)d_in[10];
  const float* nsb  = (const float*)d_in[11];
  const float* nmw  = (const float*)d_in[12];
  const float* nmb  = (const float*)d_in[13];
  const float* smu  = (const float*)d_in[14];
  const float* slog = (const float*)d_in[15];
  const float* Wq   = (const float*)d_in[16];
  const float* Wk   = (const float*)d_in[17];
  const float* Wv   = (const float*)d_in[18];
  const float* wih  = (const float*)d_in[19];
  const float* whh  = (const float*)d_in[20];
  const float* bih  = (const float*)d_in[21];
  const float* bhh  = (const float*)d_in[22];
  const float* w1   = (const float*)d_in[23];
  const float* b1   = (const float*)d_in[24];
  const float* w2   = (const float*)d_in[25];
  const float* b2   = (const float*)d_in[26];
  const float* hwt  = (const float*)d_in[27];
  const float* hb   = (const float*)d_in[28];
  const float* noise= (const float*)d_in[29];

  char* ws = (char*)d_ws;
  bf16*  kbuf  = (bf16*)(ws);
  bf16*  vT    = (bf16*)(ws + (size_t)33554432);
  bf16*  wconv = (bf16*)(ws + (size_t)67108864);
  bf16*  wkv   = (bf16*)(ws + (size_t)67174400);
  float* sb0   = (float*)(ws + (size_t)67190784);
  float* sb1   = (float*)(ws + (size_t)67452928);
  bf16*  updA  = (bf16*)(ws + (size_t)67715072);
  bf16*  updB  = (bf16*)(ws + (size_t)69812224);
  float* colA  = (float*)(ws + (size_t)71909376);
  float* colB  = (float*)(ws + (size_t)71974912);

  k0_convert<<<dim3(64), dim3(256), 0, stream>>>(c1w, c2w, Wk, Wv, wconv, wkv);
  k1_conv_kv<<<dim3(4096), dim3(256), 0, stream>>>(x1, x2, c1b, c2b, nw, nb, niw, nib,
                                                   wconv, wkv, kbuf, vT);
  // it 0: init -> sb0, updA/colA
  kA<<<dim3(2048), dim3(256), 0, stream>>>(0, kbuf, vT, smu, slog, noise,
      nsw, nsb, nmw, nmb, Wq, wih, whh, bih, bhh, w1, b1, w2, b2,
      nullptr, sb0, nullptr, updA, nullptr, colA);
  // it 1: sb0 + updA -> sb1, updB/colB
  kA<<<dim3(2048), dim3(256), 0, stream>>>(1, kbuf, vT, smu, slog, noise,
      nsw, nsb, nmw, nmb, Wq, wih, whh, bih, bhh, w1, b1, w2, b2,
      sb0, sb1, updA, updB, colA, colB);
  // it 2: sb1 + updB -> sb0, updA/colA
  kA<<<dim3(2048), dim3(256), 0, stream>>>(1, kbuf, vT, smu, slog, noise,
      nsw, nsb, nmw, nmb, Wq, wih, whh, bih, bhh, w1, b1, w2, b2,
      sb1, sb0, updB, updA, colB, colA);
  // final: sb0 + updA -> head
  kBfin<<<dim3(128), dim3(256), 0, stream>>>(sb0, updA, colA,
      wih, whh, bih, bhh, w1, b1, w2, b2, nmw, nmb, hwt, hb, (float*)d_out);
}

// Round 6
// 600.990 us; speedup vs baseline: 1.2603x; 1.2603x over previous
//
#include <hip/hip_runtime.h>
#include <stdint.h>

// JointSlotFusion on MI355X (gfx950).
// ws layout (bytes):
//   kbuf  bf16[128][2048][64] @ 0           (33,554,432)  token-major
//   vT    bf16[128][64][2048] @ 33,554,432  (33,554,432)  d-major
//   wconv bf16[2][64][256]    @ 67,108,864  (65,536)
//   wkv   bf16[2][64][64]     @ 67,174,400  (16,384)

typedef __bf16 bf16;
typedef __bf16 bf16x8 __attribute__((ext_vector_type(8)));
typedef float  f32x4  __attribute__((ext_vector_type(4)));

#define MFMA16(a, b, c) __builtin_amdgcn_mfma_f32_16x16x32_bf16((a), (b), (c), 0, 0, 0)

#define ASYNC_LDS16(g, l) \
  __builtin_amdgcn_global_load_lds((const __attribute__((address_space(1))) void*)(g), \
                                   (__attribute__((address_space(3))) void*)(l), 16, 0, 0)

// ---------------- K0: weight fp32 -> bf16 ----------------
__global__ __launch_bounds__(256) void k0_convert(
    const float* __restrict__ c1w, const float* __restrict__ c2w,
    const float* __restrict__ wk,  const float* __restrict__ wvv,
    bf16* __restrict__ wconv, bf16* __restrict__ wkv)
{
  const int i = blockIdx.x * 256 + threadIdx.x;
  if (i < 16384) {
    wconv[i]         = (bf16)c1w[i];
    wconv[16384 + i] = (bf16)c2w[i];
  }
  if (i < 4096) {
    wkv[i]        = (bf16)wk[i];
    wkv[4096 + i] = (bf16)wvv[i];
  }
}

// ---------------- K1: conv1x1 + LN + LN + k/v GEMM ----------------
// (unchanged from round 5 — will now be the top dispatch so we get its counters)
__global__ __launch_bounds__(256) void k1_conv_kv(
    const float* __restrict__ x1, const float* __restrict__ x2,
    const float* __restrict__ c1b, const float* __restrict__ c2b,
    const float* __restrict__ nw,  const float* __restrict__ nb,
    const float* __restrict__ niw, const float* __restrict__ nib,
    const bf16* __restrict__ wconv, const bf16* __restrict__ wkv,
    bf16* __restrict__ kbuf, bf16* __restrict__ vT)
{
  __shared__ union {
    float xs[8 * 264];
    float T[64][65];
    bf16  tok[64][72];
  } U;

  const int bx   = blockIdx.x;
  const int tile = bx & 15;
  const int img  = (bx >> 4) & 1;
  const int b    = bx >> 5;
  const int tid  = threadIdx.x;
  const int lane = tid & 63;
  const int wvid = tid >> 6;
  const int l15  = lane & 15;
  const int quad = lane >> 4;

  const float* xp   = (img ? x2 : x1) + (size_t)b * (256 * 1024) + tile * 64;
  const int   rowin = lane >> 4;
  const int   pq    = (lane & 15) * 4;
  const float* ga0  = xp + (size_t)rowin * 1024 + pq;
  const bf16* wc    = wconv + img * (64 * 256);
  const int p = wvid * 16 + l15;

  f32x4 acc[4] = {{0.f,0.f,0.f,0.f},{0.f,0.f,0.f,0.f},{0.f,0.f,0.f,0.f},{0.f,0.f,0.f,0.f}};

  for (int step = 0; step < 8; ++step) {
    #pragma unroll
    for (int gi = 0; gi < 2; ++gi) {
      const int g = wvid * 2 + gi;
      ASYNC_LDS16(ga0 + (size_t)(step * 32 + g * 4) * 1024, &U.xs[g * 264]);
    }
    __syncthreads();
    bf16x8 af;
    #pragma unroll
    for (int j = 0; j < 8; ++j) {
      const int cl = quad * 8 + j;
      af[j] = (bf16)U.xs[(cl >> 2) * 264 + (cl & 3) * 64 + p];
    }
    #pragma unroll
    for (int nt = 0; nt < 4; ++nt) {
      const bf16x8 bw = *(const bf16x8*)&wc[(nt * 16 + l15) * 256 + step * 32 + quad * 8];
      acc[nt] = MFMA16(af, bw, acc[nt]);
    }
    __syncthreads();
  }

  {
    const float* cb = img ? c2b : c1b;
    #pragma unroll
    for (int nt = 0; nt < 4; ++nt) {
      const int d = nt * 16 + l15;
      const float bias = cb[d];
      #pragma unroll
      for (int r = 0; r < 4; ++r)
        U.T[wvid * 16 + quad * 4 + r][d] = acc[nt][r] + bias;
    }
  }
  __syncthreads();

  float yv[16];
  {
    const int pix = tid >> 2, part = tid & 3;
    float xv[16];
    float s = 0.f, s2 = 0.f;
    #pragma unroll
    for (int i = 0; i < 16; ++i) {
      xv[i] = U.T[pix][part * 16 + i];
      s += xv[i]; s2 += xv[i] * xv[i];
    }
    s  += __shfl_xor(s, 1);  s  += __shfl_xor(s, 2);
    s2 += __shfl_xor(s2, 1); s2 += __shfl_xor(s2, 2);
    float mu   = s * 0.015625f;
    float rstd = rsqrtf(s2 * 0.015625f - mu * mu + 1e-5f);
    s = 0.f; s2 = 0.f;
    #pragma unroll
    for (int i = 0; i < 16; ++i) {
      const int d = part * 16 + i;
      const float y = (xv[i] - mu) * rstd * nw[d] + nb[d];
      yv[i] = y; s += y; s2 += y * y;
    }
    s  += __shfl_xor(s, 1);  s  += __shfl_xor(s, 2);
    s2 += __shfl_xor(s2, 1); s2 += __shfl_xor(s2, 2);
    mu   = s * 0.015625f;
    rstd = rsqrtf(s2 * 0.015625f - mu * mu + 1e-5f);
    #pragma unroll
    for (int i = 0; i < 16; ++i) {
      const int d = part * 16 + i;
      yv[i] = (yv[i] - mu) * rstd * niw[d] + nib[d];
    }
  }
  __syncthreads();
  {
    const int pix = tid >> 2, part = tid & 3;
    #pragma unroll
    for (int i = 0; i < 16; ++i) U.tok[pix][part * 16 + i] = (bf16)yv[i];
  }
  __syncthreads();

  f32x4 ak[4] = {{0.f,0.f,0.f,0.f},{0.f,0.f,0.f,0.f},{0.f,0.f,0.f,0.f},{0.f,0.f,0.f,0.f}};
  f32x4 av[4] = {{0.f,0.f,0.f,0.f},{0.f,0.f,0.f,0.f},{0.f,0.f,0.f,0.f},{0.f,0.f,0.f,0.f}};
  #pragma unroll
  for (int k0 = 0; k0 < 64; k0 += 32) {
    const bf16x8 af = *(const bf16x8*)&U.tok[wvid * 16 + l15][k0 + quad * 8];
    #pragma unroll
    for (int nt = 0; nt < 4; ++nt) {
      const bf16x8 bk = *(const bf16x8*)&wkv[(nt * 16 + l15) * 64 + k0 + quad * 8];
      const bf16x8 bv = *(const bf16x8*)&wkv[4096 + (nt * 16 + l15) * 64 + k0 + quad * 8];
      ak[nt] = MFMA16(af, bk, ak[nt]);
      av[nt] = MFMA16(af, bv, av[nt]);
    }
  }
  __syncthreads();

  #pragma unroll
  for (int nt = 0; nt < 4; ++nt)
    #pragma unroll
    for (int r = 0; r < 4; ++r)
      U.T[wvid * 16 + quad * 4 + r][nt * 16 + l15] = ak[nt][r];
  __syncthreads();
  {
    const int row = tid >> 2, dd = (tid & 3) * 16;
    const size_t kb = ((size_t)b * 2048 + img * 1024 + tile * 64) * 64;
    bf16 tb[16];
    #pragma unroll
    for (int i = 0; i < 16; ++i) tb[i] = (bf16)U.T[row][dd + i];
    *(bf16x8*)&kbuf[kb + (size_t)row * 64 + dd]     = *(bf16x8*)&tb[0];
    *(bf16x8*)&kbuf[kb + (size_t)row * 64 + dd + 8] = *(bf16x8*)&tb[8];
  }
  __syncthreads();
  #pragma unroll
  for (int nt = 0; nt < 4; ++nt)
    #pragma unroll
    for (int r = 0; r < 4; ++r)
      U.T[nt * 16 + l15][wvid * 16 + quad * 4 + r] = av[nt][r];
  __syncthreads();
  {
    const int row = tid >> 2, dd = (tid & 3) * 16;
    bf16 tb[16];
    #pragma unroll
    for (int i = 0; i < 16; ++i) tb[i] = (bf16)U.T[row][dd + i];
    const size_t vb = ((size_t)b * 64 + row) * 2048 + img * 1024 + tile * 64 + dd;
    *(bf16x8*)&vT[vb]     = *(bf16x8*)&tb[0];
    *(bf16x8*)&vT[vb + 8] = *(bf16x8*)&tb[8];
  }
}

// ---------------- kIter: entire slot-attention phase, one block per batch ----------------
// 128 blocks x 512 threads (8 waves). Wave w owns tokens [w*256, w*256+256).
// v held in registers (B-frags, loaded once); k streamed (L2-hit after iter 0);
// attn + upd partials + GRU/MLP all in LDS. 3 iterations + head, zero extra launches.
__global__ __launch_bounds__(512, 2) void kIter(
    const bf16* __restrict__ kbuf, const bf16* __restrict__ vT,
    const float* __restrict__ smu, const float* __restrict__ slog,
    const float* __restrict__ noise,
    const float* __restrict__ nsw, const float* __restrict__ nsb,
    const float* __restrict__ nmw, const float* __restrict__ nmb,
    const float* __restrict__ Wq,
    const float* __restrict__ wih, const float* __restrict__ whh,
    const float* __restrict__ bih, const float* __restrict__ bhh,
    const float* __restrict__ w1,  const float* __restrict__ b1,
    const float* __restrict__ w2,  const float* __restrict__ b2,
    const float* __restrict__ hwt, const float* __restrict__ hb,
    float* __restrict__ out)
{
  __shared__ bf16  attn[8][2064];    // 33,024 B; stride 2064 -> conflict-free b128 A-frag reads
  __shared__ bf16  updw[8][8][64];   // 8,192 B per-wave PV partials
  __shared__ float scrg[4][8][64];   // 8,192 B gru gates (sr,sz,inn,hn)
  __shared__ float h1s[8][132];      // 4,224 B mlp hidden
  __shared__ float slots[8][66];
  __shared__ float tmp[8][66];
  __shared__ bf16  qs[16][72];       // rows 8..15 zero
  __shared__ float cswave[8][8];

  const int b    = blockIdx.x;
  const int tid  = threadIdx.x;
  const int lane = tid & 63;
  const int w    = tid >> 6;          // 0..7
  const int l15  = lane & 15;
  const int quad = lane >> 4;
  const int part = lane & 7;
  const int sl   = lane >> 3;
  const int s0   = tid >> 6, d0 = tid & 63;

  // ---- load v fragments into registers: vf[kg][nt] ----
  bf16x8 vf[8][4];
  {
    const bf16* vb = vT + (size_t)b * 131072 + w * 256 + quad * 8;
    #pragma unroll
    for (int kg = 0; kg < 8; ++kg)
      #pragma unroll
      for (int nt = 0; nt < 4; ++nt)
        vf[kg][nt] = *(const bf16x8*)&vb[(size_t)(nt * 16 + l15) * 2048 + kg * 32];
  }

  // zero qs pad rows (8..15), init slots
  qs[8 + (tid >> 6)][tid & 63] = (bf16)0.f;
  slots[s0][d0] = smu[d0] + expf(slog[d0]) * noise[(size_t)b * 512 + tid];
  __syncthreads();

  for (int it = 0; it < 3; ++it) {
    // ---- LN(ns) + q ----
    {
      const float v = slots[w][lane];
      float s = v, s2 = v * v;
      #pragma unroll
      for (int m = 1; m < 64; m <<= 1) { s += __shfl_xor(s, m); s2 += __shfl_xor(s2, m); }
      const float mu = s * 0.015625f;
      const float rstd = rsqrtf(s2 * 0.015625f - mu * mu + 1e-5f);
      tmp[w][lane] = (v - mu) * rstd * nsw[lane] + nsb[lane];
    }
    __syncthreads();
    {
      float tm[8];
      #pragma unroll
      for (int i = 0; i < 8; ++i) tm[i] = tmp[sl][part * 8 + i];
      #pragma unroll
      for (int orr = 0; orr < 8; ++orr) {
        const int d = orr * 8 + w;
        const f32x4 w0 = *(const f32x4*)&Wq[d * 64 + part * 8];
        const f32x4 w1v = *(const f32x4*)&Wq[d * 64 + part * 8 + 4];
        float a = tm[0]*w0[0] + tm[1]*w0[1] + tm[2]*w0[2] + tm[3]*w0[3]
                + tm[4]*w1v[0] + tm[5]*w1v[1] + tm[6]*w1v[2] + tm[7]*w1v[3];
        a += __shfl_xor(a, 1); a += __shfl_xor(a, 2); a += __shfl_xor(a, 4);
        if (part == 0) qs[sl][d] = (bf16)(a * 0.125f);
      }
    }
    __syncthreads();

    // ---- logits + per-token softmax over s=8; wave w handles its 256 tokens ----
    {
      float cs = 0.f;
      #pragma unroll 2
      for (int g = 0; g < 16; ++g) {
        const int tok0 = w * 256 + g * 16;
        const bf16* kr = kbuf + ((size_t)b * 2048 + tok0 + l15) * 64 + quad * 8;
        f32x4 lg = {0.f, 0.f, 0.f, 0.f};
        lg = MFMA16(*(const bf16x8*)&kr[0],  *(const bf16x8*)&qs[l15][quad * 8],      lg);
        lg = MFMA16(*(const bf16x8*)&kr[32], *(const bf16x8*)&qs[l15][32 + quad * 8], lg);
        #pragma unroll
        for (int r = 0; r < 4; ++r) {
          const float l = lg[r];
          float m = l;
          m = fmaxf(m, __shfl_xor(m, 1));
          m = fmaxf(m, __shfl_xor(m, 2));
          m = fmaxf(m, __shfl_xor(m, 4));
          const float e = expf(l - m);
          float ss = e;
          ss += __shfl_xor(ss, 1);
          ss += __shfl_xor(ss, 2);
          ss += __shfl_xor(ss, 4);
          const float at = e / ss + 1e-8f;
          if (l15 < 8) {
            const bf16 ab = (bf16)at;
            attn[l15][tok0 + quad * 4 + r] = ab;
            cs += (float)ab;
          }
        }
      }
      cs += __shfl_xor(cs, 16);
      cs += __shfl_xor(cs, 32);
      if (lane < 8) cswave[w][lane] = cs;
    }
    __syncthreads();

    // ---- PV: A = attn rows (zero for l15>=8), B = vf registers ----
    {
      f32x4 acc[4] = {{0.f,0.f,0.f,0.f},{0.f,0.f,0.f,0.f},{0.f,0.f,0.f,0.f},{0.f,0.f,0.f,0.f}};
      #pragma unroll
      for (int kg = 0; kg < 8; ++kg) {
        bf16x8 afr;
        if (l15 < 8) {
          afr = *(const bf16x8*)&attn[l15][w * 256 + kg * 32 + quad * 8];
        } else {
          #pragma unroll
          for (int j = 0; j < 8; ++j) afr[j] = (bf16)0.f;
        }
        #pragma unroll
        for (int nt = 0; nt < 4; ++nt) acc[nt] = MFMA16(afr, vf[kg][nt], acc[nt]);
      }
      if (quad < 2) {
        #pragma unroll
        for (int nt = 0; nt < 4; ++nt)
          #pragma unroll
          for (int r = 0; r < 4; ++r)
            updw[w][quad * 4 + r][nt * 16 + l15] = (bf16)acc[nt][r];
      }
    }
    __syncthreads();

    // ---- reduce partials -> updates (tmp) ----
    {
      float u = 0.f;
      #pragma unroll
      for (int ww = 0; ww < 8; ++ww) u += (float)updw[ww][s0][d0];
      float cs = 0.f;
      #pragma unroll
      for (int ww = 0; ww < 8; ++ww) cs += cswave[ww][s0];
      tmp[s0][d0] = u / cs;
    }
    __syncthreads();

    // ---- GRU gates ----
    {
      float tv[8], sv[8];
      #pragma unroll
      for (int i = 0; i < 8; ++i) { tv[i] = tmp[sl][part * 8 + i]; sv[i] = slots[sl][part * 8 + i]; }
      #pragma unroll 4
      for (int jr = 0; jr < 24; ++jr) {
        const int j = jr * 8 + w;
        const f32x4 wa0 = *(const f32x4*)&wih[j * 64 + part * 8];
        const f32x4 wa1 = *(const f32x4*)&wih[j * 64 + part * 8 + 4];
        const f32x4 wb0 = *(const f32x4*)&whh[j * 64 + part * 8];
        const f32x4 wb1 = *(const f32x4*)&whh[j * 64 + part * 8 + 4];
        float a = tv[0]*wa0[0] + tv[1]*wa0[1] + tv[2]*wa0[2] + tv[3]*wa0[3]
                + tv[4]*wa1[0] + tv[5]*wa1[1] + tv[6]*wa1[2] + tv[7]*wa1[3];
        float h = sv[0]*wb0[0] + sv[1]*wb0[1] + sv[2]*wb0[2] + sv[3]*wb0[3]
                + sv[4]*wb1[0] + sv[5]*wb1[1] + sv[6]*wb1[2] + sv[7]*wb1[3];
        a += __shfl_xor(a, 1); a += __shfl_xor(a, 2); a += __shfl_xor(a, 4);
        h += __shfl_xor(h, 1); h += __shfl_xor(h, 2); h += __shfl_xor(h, 4);
        if (part == 0) {
          const float gi_ = a + bih[j], gh_ = h + bhh[j];
          if (j < 64)       scrg[0][sl][j] = gi_ + gh_;
          else if (j < 128) scrg[1][sl][j - 64] = gi_ + gh_;
          else { scrg[2][sl][j - 128] = gi_; scrg[3][sl][j - 128] = gh_; }
        }
      }
    }
    __syncthreads();
    {
      const float r  = 1.f / (1.f + expf(-scrg[0][s0][d0]));
      const float z  = 1.f / (1.f + expf(-scrg[1][s0][d0]));
      const float nn = tanhf(scrg[2][s0][d0] + r * scrg[3][s0][d0]);
      slots[s0][d0] = (1.f - z) * nn + z * slots[s0][d0];
    }
    __syncthreads();
    // ---- LN(nm) -> tmp ----
    {
      const float v = slots[w][lane];
      float s = v, s2 = v * v;
      #pragma unroll
      for (int m = 1; m < 64; m <<= 1) { s += __shfl_xor(s, m); s2 += __shfl_xor(s2, m); }
      const float mu = s * 0.015625f;
      const float rstd = rsqrtf(s2 * 0.015625f - mu * mu + 1e-5f);
      tmp[w][lane] = (v - mu) * rstd * nmw[lane] + nmb[lane];
    }
    __syncthreads();
    // ---- MLP hidden ----
    {
      float tm[8];
      #pragma unroll
      for (int i = 0; i < 8; ++i) tm[i] = tmp[sl][part * 8 + i];
      #pragma unroll 4
      for (int jr = 0; jr < 16; ++jr) {
        const int j = jr * 8 + w;
        const f32x4 w0 = *(const f32x4*)&w1[j * 64 + part * 8];
        const f32x4 w1v = *(const f32x4*)&w1[j * 64 + part * 8 + 4];
        float a = tm[0]*w0[0] + tm[1]*w0[1] + tm[2]*w0[2] + tm[3]*w0[3]
                + tm[4]*w1v[0] + tm[5]*w1v[1] + tm[6]*w1v[2] + tm[7]*w1v[3];
        a += __shfl_xor(a, 1); a += __shfl_xor(a, 2); a += __shfl_xor(a, 4);
        if (part == 0) h1s[sl][j] = fmaxf(a + b1[j], 0.f);
      }
    }
    __syncthreads();
    // ---- MLP out + residual ----
    #pragma unroll
    for (int orr = 0; orr < 8; ++orr) {
      const int d = orr * 8 + w;
      float a = 0.f;
      #pragma unroll
      for (int i = 0; i < 4; ++i) {
        const f32x4 wv4 = *(const f32x4*)&w2[d * 128 + part * 16 + i * 4];
        a += h1s[sl][part * 16 + i * 4 + 0] * wv4[0] + h1s[sl][part * 16 + i * 4 + 1] * wv4[1]
           + h1s[sl][part * 16 + i * 4 + 2] * wv4[2] + h1s[sl][part * 16 + i * 4 + 3] * wv4[3];
      }
      a += __shfl_xor(a, 1); a += __shfl_xor(a, 2); a += __shfl_xor(a, 4);
      if (part == 0) slots[sl][d] += a + b2[d];
    }
    __syncthreads();
  }

  // ---- head ----
  if (tid < 64) {
    float f = 0.f;
    #pragma unroll
    for (int s = 0; s < 8; ++s) f += slots[s][tid];
    tmp[0][tid] = f * 0.125f;
  }
  __syncthreads();
  if (tid < 15) {
    float a = hb[tid];
    for (int d = 0; d < 64; ++d) a += tmp[0][d] * hwt[tid * 64 + d];
    out[b * 15 + tid] = a;
  }
}

extern "C" void kernel_launch(void* const* d_in, const int* in_sizes, int n_in,
                              void* d_out, int out_size, void* d_ws, size_t ws_size,
                              hipStream_t stream) {
  const float* x1   = (const float*)d_in[0];
  const float* x2   = (const float*)d_in[1];
  const float* c1w  = (const float*)d_in[2];
  const float* c1b  = (const float*)d_in[3];
  const float* c2w  = (const float*)d_in[4];
  const float* c2b  = (const float*)d_in[5];
  const float* nw   = (const float*)d_in[6];
  const float* nb   = (const float*)d_in[7];
  const float* niw  = (const float*)d_in[8];
  const float* nib  = (const float*)d_in[9];
  const float* nsw  = (const float*)d_in[10];
  const float* nsb  = (const float*)d_in[11];
  const float* nmw  = (const float*)d_in[12];
  const float* nmb  = (const float*)d_in[13];
  const float* smu  = (const float*)d_in[14];
  const float* slog = (const float*)d_in[15];
  const float* Wq   = (const float*)d_in[16];
  const float* Wk   = (const float*)d_in[17];
  const float* Wv   = (const float*)d_in[18];
  const float* wih  = (const float*)d_in[19];
  const float* whh  = (const float*)d_in[20];
  const float* bih  = (const float*)d_in[21];
  const float* bhh  = (const float*)d_in[22];
  const float* w1   = (const float*)d_in[23];
  const float* b1   = (const float*)d_in[24];
  const float* w2   = (const float*)d_in[25];
  const float* b2   = (const float*)d_in[26];
  const float* hwt  = (const float*)d_in[27];
  const float* hb   = (const float*)d_in[28];
  const float* noise= (const float*)d_in[29];

  char* ws = (char*)d_ws;
  bf16*  kbuf  = (bf16*)(ws);
  bf16*  vT    = (bf16*)(ws + (size_t)33554432);
  bf16*  wconv = (bf16*)(ws + (size_t)67108864);
  bf16*  wkv   = (bf16*)(ws + (size_t)67174400);

  k0_convert<<<dim3(64), dim3(256), 0, stream>>>(c1w, c2w, Wk, Wv, wconv, wkv);
  k1_conv_kv<<<dim3(4096), dim3(256), 0, stream>>>(x1, x2, c1b, c2b, nw, nb, niw, nib,
                                                   wconv, wkv, kbuf, vT);
  kIter<<<dim3(128), dim3(512), 0, stream>>>(kbuf, vT, smu, slog, noise,
      nsw, nsb, nmw, nmb, Wq, wih, whh, bih, bhh, w1, b1, w2, b2,
      hwt, hb, (float*)d_out);
}